// Round 6
// baseline (13948.819 us; speedup 1.0000x reference)
//
#include <hip/hip_runtime.h>
#include <stdint.h>

// Problem constants
#define NB 256      // batch
#define NS 512      // seq
#define NV 32       // vocab
#define NE 128      // embed
#define NH 512      // rnn units
#define N4H 2048    // 4*H

typedef __attribute__((ext_vector_type(8))) short short8;
typedef __attribute__((ext_vector_type(4))) float f32x4;
typedef __attribute__((ext_vector_type(4))) unsigned int u32x4;
typedef __attribute__((ext_vector_type(4))) unsigned short u16x4;

__device__ __forceinline__ float bf2f(unsigned short u){
  unsigned int x = ((unsigned int)u) << 16;
  return __builtin_bit_cast(float, x);
}
__device__ __forceinline__ unsigned short f2bf(float f){
  unsigned int u = __builtin_bit_cast(unsigned int, f);
  u += 0x7fffu + ((u >> 16) & 1u);
  return (unsigned short)(u >> 16);
}
// async global->LDS, 16B per lane; LDS dest = wave-uniform base + lane*16
__device__ __forceinline__ void gload_lds16(const void* g, void* l){
  __builtin_amdgcn_global_load_lds(
      (const __attribute__((address_space(1))) unsigned int*)(uintptr_t)g,
      (__attribute__((address_space(3))) unsigned int*)(uintptr_t)l,
      16, 0, 0);
}

// ---------------------------------------------------------------------------
// Transpose + cast f32 [K][N] -> bf16 [N][K]
// ---------------------------------------------------------------------------
__global__ __launch_bounds__(256) void transpose_cast(
    const float* __restrict__ in, unsigned short* __restrict__ out, int K, int N)
{
  int k = blockIdx.x * 256 + threadIdx.x;
  int n = blockIdx.y;
  if (k < K) out[(long)n * K + k] = f2bf(in[(long)k * N + n]);
}

// ---------------------------------------------------------------------------
// Embedding (time-major): x0[t][b][e] = bf16(emb[tok[b][t]][e] * sqrt(128))
// ---------------------------------------------------------------------------
__global__ __launch_bounds__(256) void embed_kernel(
    const int* __restrict__ tok, const float* __restrict__ emb,
    unsigned short* __restrict__ x0)
{
  long gid = (long)blockIdx.x * 256 + threadIdx.x;
  long idx = gid * 4;                     // element index into [NS][NB][NE]
  int e = (int)(idx & 127);
  int b = (int)((idx >> 7) & 255);
  int t = (int)(idx >> 15);
  int tk = tok[b * NS + t];
  f32x4 v = *(const f32x4*)(emb + (long)tk * NE + e);
  u16x4 o;
  #pragma unroll
  for (int i = 0; i < 4; ++i) o[i] = f2bf(v[i] * 11.313708498984761f);
  *(u16x4*)(x0 + idx) = o;
}

// ---------------------------------------------------------------------------
// GEMM: C[M][N] = A[M][K] * BT[N][K]^T  (+bias, +relu, f32/bf16 out, row remap)
// m97-style: 256 thr, BK=64, global_load_lds staging, 16x16x32 bf16 MFMA
// (used for the dense head only)
// ---------------------------------------------------------------------------
template<int BM, int BN, bool BIAS, bool RELU, bool F32OUT, bool REMAP>
__global__ __launch_bounds__(256) void gemm_bt(
    const unsigned short* __restrict__ A, const unsigned short* __restrict__ BT,
    void* __restrict__ Cv, const float* __restrict__ bias,
    int M, int N, int K, int rowoff)
{
  constexpr int BK = 64;
  constexpr int WN = (BN >= 64) ? 2 : 1;
  constexpr int WM = 4 / WN;
  constexpr int WTM = BM / WM, WTN = BN / WN;
  constexpr int FM = WTM / 16, FN = WTN / 16;
  __shared__ unsigned short lds[(BM + BN) * BK];
  unsigned short* As = lds;
  unsigned short* Bs = lds + BM * BK;
  const int tid = threadIdx.x;
  const int w = tid >> 6, l = tid & 63;
  const int n0 = blockIdx.x * BN, m0 = blockIdx.y * BM;
  const int wm = (WN == 2) ? (w >> 1) : w;
  const int wn = (WN == 2) ? (w & 1) : 0;

  f32x4 acc[FM][FN];
  #pragma unroll
  for (int i = 0; i < FM; i++)
    #pragma unroll
    for (int j = 0; j < FN; j++) acc[i][j] = (f32x4)0.f;

  constexpr int CH_A = BM * 8;            // 16B chunks in A region
  constexpr int CH_T = (BM + BN) * 8;
  constexpr int PW = CH_T / 4;
  static_assert(PW % 64 == 0, "staging alignment");
  static_assert(CH_A % 64 == 0, "region boundary alignment");

  for (int kt = 0; kt < K; kt += BK) {
    #pragma unroll
    for (int i = 0; i < PW / 64; ++i) {
      int c0 = w * PW + i * 64;           // wave-uniform
      int c = c0 + l;
      const unsigned short* g;
      if (c0 < CH_A) {
        int row = c >> 3, col = c & 7;
        g = A + (long)(m0 + row) * K + kt + col * 8;
      } else {
        int cb = c - CH_A;
        int row = cb >> 3, col = cb & 7;
        g = BT + (long)(n0 + row) * K + kt + col * 8;
      }
      gload_lds16(g, lds + (size_t)c0 * 8);
    }
    __syncthreads();
    #pragma unroll
    for (int ks = 0; ks < BK / 32; ++ks) {
      short8 a[FM], b[FN];
      #pragma unroll
      for (int mt = 0; mt < FM; ++mt)
        a[mt] = *(const short8*)&As[(wm * WTM + mt * 16 + (l & 15)) * BK + ks * 32 + (l >> 4) * 8];
      #pragma unroll
      for (int nt = 0; nt < FN; ++nt)
        b[nt] = *(const short8*)&Bs[(wn * WTN + nt * 16 + (l & 15)) * BK + ks * 32 + (l >> 4) * 8];
      #pragma unroll
      for (int mt = 0; mt < FM; ++mt)
        #pragma unroll
        for (int nt = 0; nt < FN; ++nt)
          acc[mt][nt] = __builtin_amdgcn_mfma_f32_16x16x32_bf16(a[mt], b[nt], acc[mt][nt], 0, 0, 0);
    }
    __syncthreads();
  }

  const int row_l = l >> 4, col_l = l & 15;
  #pragma unroll
  for (int nt = 0; nt < FN; ++nt) {
    int col = n0 + wn * WTN + nt * 16 + col_l;
    float bv = 0.f;
    if (BIAS) bv = bias[col];
    #pragma unroll
    for (int mt = 0; mt < FM; ++mt) {
      #pragma unroll
      for (int i = 0; i < 4; ++i) {
        int m = m0 + wm * WTM + mt * 16 + row_l * 4 + i;
        float v = acc[mt][nt][i] + bv;
        if (RELU) v = v > 0.f ? v : 0.f;
        long cidx;
        if (REMAP) {
          int gr = rowoff + m;            // global time-major row = t*NB + b
          int b_ = gr & (NB - 1), t_ = gr >> 8;
          cidx = ((long)b_ * NS + t_) * N + col;
        } else {
          cidx = (long)m * N + col;
        }
        if (F32OUT) ((float*)Cv)[cidx] = v;
        else ((unsigned short*)Cv)[cidx] = f2bf(v);
      }
    }
  }
}

// ---------------------------------------------------------------------------
// Fused LSTM scan, round 6: persistent weights in VGPRs + wave specialization.
// 256 WGs = 8 batch-groups x 32 unit-slices; WG = 4 waves, 1 WG/CU (VGPR-bound).
//   waves 0-1 (zx): W-frags persistent in regs; MFMA x[t] (prefetched to regs
//     last step) -> Zlx; prefetch x[t+1]. Wave 0 additionally publishes
//     h[t-1] (one dwordx4/lane sc0sc1 store + one no-return atomic_add on the
//     group counter); wave 1 writes x_out[t-1] (cached path).
//   waves 2-3 (zh): U-frags persistent in regs; poll group counter >= 32*t
//     (single padded word -> 1 coalesced MALL req/wave), then 32 direct
//     per-lane dwordx4 sc0sc1 loads of h[t-1] (layout = A-frag mapping, no
//     LDS staging), 64 MFMA -> Zlh.
// Gates phase (all 256 threads): z = Zlx + Zlh, fp32 LSTM math, h -> hpack.
// Aggregate counter >= 32*t implies all h[t-1] visible AND all h[t-2] readers
// done => 2-parity h_buf safe. No cache-wide fences anywhere.
// ---------------------------------------------------------------------------
template<int KD>
__global__ __launch_bounds__(256, 1) void lstm_scan_fused(
    const unsigned short* __restrict__ x_in,  // [NS][NB][KD] bf16
    const unsigned short* __restrict__ WT,    // [2048][KD] bf16
    const unsigned short* __restrict__ UT,    // [2048][512] bf16
    const float* __restrict__ bias,           // [2048] f32
    unsigned short* __restrict__ x_out,       // [NS][NB][512] bf16
    unsigned short* __restrict__ h_buf,       // [2][8][16 ks][32 r][32 n] bf16
    unsigned int* __restrict__ cnt)           // [8] padded x16 (this layer)
{
  constexpr int KS = KD / 32;
  __shared__ float Zlx[32 * 65];
  __shared__ float Zlh[32 * 65];
  __shared__ unsigned short hpack[32 * 16];   // [r][j] bf16, 1 KB

  const int tid = threadIdx.x, wv = tid >> 6, l = tid & 63;
  const int group = blockIdx.x & 7;
  const int slice = blockIdx.x >> 3;
  const int u0 = slice * 16;
  const int lr = l & 15, lk = l >> 4;        // frag row / k-quad
  const int j2 = tid & 15, r0 = tid >> 4;    // gates cell mapping (r0 in 0..15)
  const int wz = wv & 1;                     // gate-pair index within role

  // ---- persistent weight fragments (W for zx waves, U for zh waves)
  short8 wfrag[2][16];
  float bv0 = 0.f, bv1 = 0.f;
  if (wv < 2) {
    #pragma unroll
    for (int g = 0; g < 2; ++g)
      #pragma unroll
      for (int ks = 0; ks < KS; ++ks)
        wfrag[g][ks] = *(const short8*)(WT + (size_t)((2 * wz + g) * NH + u0 + lr) * KD + ks * 32 + lk * 8);
    bv0 = bias[(2 * wz + 0) * NH + u0 + lr];
    bv1 = bias[(2 * wz + 1) * NH + u0 + lr];
  } else {
    #pragma unroll
    for (int g = 0; g < 2; ++g)
      #pragma unroll
      for (int ks = 0; ks < 16; ++ks)
        wfrag[g][ks] = *(const short8*)(UT + (size_t)((2 * wz + g) * NH + u0 + lr) * NH + ks * 32 + lk * 8);
  }

  // ---- zx x-fragment registers, preloaded for t=0
  short8 xa[2][16];
  const unsigned short* xp0 = x_in + (size_t)(group * 32 + lr) * KD + lk * 8;
  if (wv < 2) {
    #pragma unroll
    for (int m = 0; m < 2; ++m)
      #pragma unroll
      for (int ks = 0; ks < KS; ++ks)
        xa[m][ks] = *(const short8*)(xp0 + (size_t)m * 16 * KD + ks * 32);
  }

  // ---- pointers
  unsigned short* hd0 = h_buf + group * 16384 + (slice >> 1) * 1024 + (slice & 1) * 16
                        + (l >> 1) * 32 + (l & 1) * 8;             // publish (wave 0)
  unsigned short* xo0 = x_out + (size_t)(group * 32 + (l >> 1)) * NH + u0 + (l & 1) * 8; // x_out (wave 1)
  const unsigned short* hb0 = h_buf + group * 16384 + lr * 32 + lk * 8;  // zh gather
  unsigned int* cp = cnt + group * 16;
  const unsigned int one = 1u;

  // ---- zero Zlh (t=0 reads it)
  for (int i = tid; i < 32 * 65; i += 256) Zlh[i] = 0.f;
  __syncthreads();

  float c0 = 0.f, c1 = 0.f;

  for (int t = 0; t < NS; ++t) {
    if (wv == 0) {
      if (t > 0) {
        // publish h[t-1]: hpack -> MALL, drain, bump group counter
        u32x4 hv = *(const u32x4*)((const char*)hpack + l * 16);
        unsigned short* hd = hd0 + (size_t)((t - 1) & 1) * 131072;
        asm volatile("global_store_dwordx4 %0, %1, off sc0 sc1"
                     :: "v"(hd), "v"(hv) : "memory");
        asm volatile("s_waitcnt vmcnt(0)" ::: "memory");
        if (l == 0)
          asm volatile("global_atomic_add %0, %1, off sc1"
                       :: "v"(cp), "v"(one) : "memory");
      }
    } else if (wv == 1) {
      if (t > 0) {
        // x_out[t-1] from hpack (cached path)
        u32x4 hv = *(const u32x4*)((const char*)hpack + l * 16);
        *(u32x4*)(xo0 + (size_t)(t - 1) * NB * NH) = hv;
      }
    }

    if (wv < 2) {
      // ---- zx: MFMA from persistent regs; acc init = bias
      f32x4 a00 = {bv0, bv0, bv0, bv0}, a01 = {bv0, bv0, bv0, bv0};
      f32x4 a10 = {bv1, bv1, bv1, bv1}, a11 = {bv1, bv1, bv1, bv1};
      #pragma unroll
      for (int ks = 0; ks < KS; ++ks) {
        a00 = __builtin_amdgcn_mfma_f32_16x16x32_bf16(xa[0][ks], wfrag[0][ks], a00, 0, 0, 0);
        a01 = __builtin_amdgcn_mfma_f32_16x16x32_bf16(xa[1][ks], wfrag[0][ks], a01, 0, 0, 0);
        a10 = __builtin_amdgcn_mfma_f32_16x16x32_bf16(xa[0][ks], wfrag[1][ks], a10, 0, 0, 0);
        a11 = __builtin_amdgcn_mfma_f32_16x16x32_bf16(xa[1][ks], wfrag[1][ks], a11, 0, 0, 0);
      }
      #pragma unroll
      for (int i = 0; i < 4; ++i) {
        Zlx[(lk * 4 + i) * 65      + (2 * wz + 0) * 16 + lr] = a00[i];
        Zlx[(16 + lk * 4 + i) * 65 + (2 * wz + 0) * 16 + lr] = a01[i];
        Zlx[(lk * 4 + i) * 65      + (2 * wz + 1) * 16 + lr] = a10[i];
        Zlx[(16 + lk * 4 + i) * 65 + (2 * wz + 1) * 16 + lr] = a11[i];
      }
      // ---- prefetch x for t+1 (clamped; clamped data never consumed)
      int tn = (t + 1 < NS) ? (t + 1) : t;
      const unsigned short* xp = xp0 + (size_t)tn * NB * KD;
      #pragma unroll
      for (int m = 0; m < 2; ++m)
        #pragma unroll
        for (int ks = 0; ks < KS; ++ks)
          xa[m][ks] = *(const short8*)(xp + (size_t)m * 16 * KD + ks * 32);
    } else if (t > 0) {
      // ---- zh: poll aggregate counter, direct-gather h frags, MFMA
      {
        unsigned int v, target = 32u * (unsigned)t;
        int spin = 0;
        do {
          asm volatile("global_load_dword %0, %1, off sc0 sc1\n\ts_waitcnt vmcnt(0)"
                       : "=v"(v) : "v"(cp) : "memory");
        } while (v < target && ++spin < (1 << 15));
      }
      const unsigned short* hb_ = hb0 + (size_t)((t - 1) & 1) * 131072;
      short8 ha[2][16];
      #pragma unroll
      for (int ks = 0; ks < 16; ++ks) {
        asm volatile("global_load_dwordx4 %0, %1, off sc0 sc1"
                     : "=v"(ha[0][ks]) : "v"(hb_ + ks * 1024) : "memory");
        asm volatile("global_load_dwordx4 %0, %1, off sc0 sc1"
                     : "=v"(ha[1][ks]) : "v"(hb_ + ks * 1024 + 512) : "memory");
      }
      asm volatile("s_waitcnt vmcnt(0)" ::: "memory");
      __builtin_amdgcn_sched_barrier(0);
      f32x4 a00 = (f32x4)0.f, a01 = (f32x4)0.f, a10 = (f32x4)0.f, a11 = (f32x4)0.f;
      #pragma unroll
      for (int ks = 0; ks < 16; ++ks) {
        a00 = __builtin_amdgcn_mfma_f32_16x16x32_bf16(ha[0][ks], wfrag[0][ks], a00, 0, 0, 0);
        a01 = __builtin_amdgcn_mfma_f32_16x16x32_bf16(ha[1][ks], wfrag[0][ks], a01, 0, 0, 0);
        a10 = __builtin_amdgcn_mfma_f32_16x16x32_bf16(ha[0][ks], wfrag[1][ks], a10, 0, 0, 0);
        a11 = __builtin_amdgcn_mfma_f32_16x16x32_bf16(ha[1][ks], wfrag[1][ks], a11, 0, 0, 0);
      }
      #pragma unroll
      for (int i = 0; i < 4; ++i) {
        Zlh[(lk * 4 + i) * 65      + (2 * wz + 0) * 16 + lr] = a00[i];
        Zlh[(16 + lk * 4 + i) * 65 + (2 * wz + 0) * 16 + lr] = a01[i];
        Zlh[(lk * 4 + i) * 65      + (2 * wz + 1) * 16 + lr] = a10[i];
        Zlh[(16 + lk * 4 + i) * 65 + (2 * wz + 1) * 16 + lr] = a11[i];
      }
    }
    __syncthreads();   // Zlx/Zlh ready

    // ---- gates (all threads; thread owns rows r0, r0+16 of col j2)
    #pragma unroll
    for (int p = 0; p < 2; ++p) {
      int r = r0 + p * 16;
      float zi = Zlx[r * 65 +      j2] + Zlh[r * 65 +      j2];
      float zf = Zlx[r * 65 + 16 + j2] + Zlh[r * 65 + 16 + j2];
      float zg = Zlx[r * 65 + 32 + j2] + Zlh[r * 65 + 32 + j2];
      float zo = Zlx[r * 65 + 48 + j2] + Zlh[r * 65 + 48 + j2];
      float ig = 1.f / (1.f + __expf(-zi));
      float fg = 1.f / (1.f + __expf(-zf));
      float gg = 1.f - 2.f / (__expf(2.f * zg) + 1.f);   // robust tanh
      float og = 1.f / (1.f + __expf(-zo));
      float cc = fg * (p ? c1 : c0) + ig * gg;
      if (p) c1 = cc; else c0 = cc;
      float th = 1.f - 2.f / (__expf(2.f * cc) + 1.f);
      hpack[r * 16 + j2] = f2bf(og * th);
    }
    __syncthreads();   // hpack ready
  }

  // ---- tail: x_out[NS-1]
  if (wv == 1) {
    u32x4 hv = *(const u32x4*)((const char*)hpack + l * 16);
    *(u32x4*)(xo0 + (size_t)(NS - 1) * NB * NH) = hv;
  }
}

// ---------------------------------------------------------------------------
extern "C" void kernel_launch(void* const* d_in, const int* in_sizes, int n_in,
                              void* d_out, int out_size, void* d_ws, size_t ws_size,
                              hipStream_t stream) {
  const int*   tokens = (const int*)  d_in[0];
  const float* emb    = (const float*)d_in[1];
  const float* w0     = (const float*)d_in[2];
  const float* u0     = (const float*)d_in[3];
  const float* b0     = (const float*)d_in[4];
  const float* w_rest = (const float*)d_in[5];
  const float* u_rest = (const float*)d_in[6];
  const float* b_rest = (const float*)d_in[7];
  const float* dw1    = (const float*)d_in[8];
  const float* db1    = (const float*)d_in[9];
  const float* dw2    = (const float*)d_in[10];
  const float* db2    = (const float*)d_in[11];
  float* out = (float*)d_out;

  char* ws = (char*)d_ws;
  size_t off = 0;
  auto alloc = [&](size_t bytes) -> char* {
    char* p = ws + off;
    off += (bytes + 255) & ~(size_t)255;
    return p;
  };
  unsigned short* ut[4];
  for (int i = 0; i < 4; ++i) ut[i] = (unsigned short*)alloc((size_t)N4H * NH * 2);
  unsigned short* w0t = (unsigned short*)alloc((size_t)N4H * NE * 2);
  unsigned short* wt[3];
  for (int i = 0; i < 3; ++i) wt[i] = (unsigned short*)alloc((size_t)N4H * NH * 2);
  unsigned short* dw1t = (unsigned short*)alloc((size_t)1024 * 512 * 2);
  unsigned short* dw2t = (unsigned short*)alloc((size_t)32 * 1024 * 2);
  unsigned short* x0  = (unsigned short*)alloc((size_t)NB * NS * NE * 2);
  unsigned short* xA  = (unsigned short*)alloc((size_t)NB * NS * NH * 2);
  unsigned short* hb  = (unsigned short*)alloc((size_t)2 * 8 * 16384 * 2);
  unsigned int*  cnt  = (unsigned int*)alloc((size_t)4 * 8 * 16 * 4);

  // head intermediate chunk buffer from remaining workspace
  size_t avail = (ws_size > off) ? (ws_size - off) : 0;
  long RC = (long)(avail / ((size_t)1024 * 2));
  if (RC > (long)NB * NS) RC = (long)NB * NS;
  RC &= ~(long)127;
  if (RC < 128) RC = 128;
  unsigned short* h1buf = (unsigned short*)alloc((size_t)RC * 1024 * 2);

  (void)hipMemsetAsync(cnt, 0, (size_t)4 * 8 * 16 * 4, stream);

  // Weight transposes (f32 [K][N] -> bf16 [N][K])
  transpose_cast<<<dim3(1, N4H), 256, 0, stream>>>(w0, w0t, NE, N4H);
  transpose_cast<<<dim3(2, N4H), 256, 0, stream>>>(u0, ut[0], NH, N4H);
  for (int i = 0; i < 3; ++i) {
    transpose_cast<<<dim3(2, N4H), 256, 0, stream>>>(w_rest + (size_t)i * NH * N4H, wt[i], NH, N4H);
    transpose_cast<<<dim3(2, N4H), 256, 0, stream>>>(u_rest + (size_t)i * NH * N4H, ut[i + 1], NH, N4H);
  }
  transpose_cast<<<dim3(2, 1024), 256, 0, stream>>>(dw1, dw1t, 512, 1024);
  transpose_cast<<<dim3(4, 32), 256, 0, stream>>>(dw2, dw2t, 1024, 32);

  embed_kernel<<<16384, 256, 0, stream>>>(tokens, emb, x0);

  // Layer 0: x0 -> xA ; layers 1-3: xA -> xA in place (protocol-ordered)
  lstm_scan_fused<NE><<<256, 256, 0, stream>>>(
      x0, w0t, ut[0], b0, xA, hb, cnt);
  for (int lyr = 1; lyr < 4; ++lyr) {
    lstm_scan_fused<NH><<<256, 256, 0, stream>>>(
        xA, wt[lyr - 1], ut[lyr], b_rest + (size_t)(lyr - 1) * N4H, xA, hb,
        cnt + (size_t)lyr * 8 * 16);
  }

  // Dense head, row-chunked through h1buf: h1 = relu(x@dw1+db1); out = h1@dw2+db2
  for (long r0 = 0; r0 < (long)NB * NS; r0 += RC) {
    long rows = ((long)NB * NS - r0 < RC) ? ((long)NB * NS - r0) : RC;
    gemm_bt<128, 128, true, true, false, false>
        <<<dim3(1024 / 128, rows / 128), 256, 0, stream>>>(
            xA + (size_t)r0 * NH, dw1t, h1buf, db1, (int)rows, 1024, NH, 0);
    gemm_bt<128, 32, true, false, true, true>
        <<<dim3(1, rows / 128), 256, 0, stream>>>(
            h1buf, dw2t, out, db2, (int)rows, 32, 1024, (int)r0);
  }
}

// Round 8
// 11500.870 us; speedup vs baseline: 1.2128x; 1.2128x over previous
//
#include <hip/hip_runtime.h>
#include <stdint.h>

// Problem constants
#define NB 256      // batch
#define NS 512      // seq
#define NV 32       // vocab
#define NE 128      // embed
#define NH 512      // rnn units
#define N4H 2048    // 4*H

typedef __attribute__((ext_vector_type(8))) short short8;
typedef __attribute__((ext_vector_type(4))) float f32x4;
typedef __attribute__((ext_vector_type(4))) unsigned int u32x4;
typedef __attribute__((ext_vector_type(4))) unsigned short u16x4;

__device__ __forceinline__ float bf2f(unsigned short u){
  unsigned int x = ((unsigned int)u) << 16;
  return __builtin_bit_cast(float, x);
}
__device__ __forceinline__ unsigned short f2bf(float f){
  unsigned int u = __builtin_bit_cast(unsigned int, f);
  u += 0x7fffu + ((u >> 16) & 1u);
  return (unsigned short)(u >> 16);
}
// async global->LDS, 16B per lane; LDS dest = wave-uniform base + lane*16
__device__ __forceinline__ void gload_lds16(const void* g, void* l){
  __builtin_amdgcn_global_load_lds(
      (const __attribute__((address_space(1))) unsigned int*)(uintptr_t)g,
      (__attribute__((address_space(3))) unsigned int*)(uintptr_t)l,
      16, 0, 0);
}

// ---------------------------------------------------------------------------
// Transpose + cast f32 [K][N] -> bf16 [N][K]
// ---------------------------------------------------------------------------
__global__ __launch_bounds__(256) void transpose_cast(
    const float* __restrict__ in, unsigned short* __restrict__ out, int K, int N)
{
  int k = blockIdx.x * 256 + threadIdx.x;
  int n = blockIdx.y;
  if (k < K) out[(long)n * K + k] = f2bf(in[(long)k * N + n]);
}

// ---------------------------------------------------------------------------
// Embedding (time-major): x0[t][b][e] = bf16(emb[tok[b][t]][e] * sqrt(128))
// ---------------------------------------------------------------------------
__global__ __launch_bounds__(256) void embed_kernel(
    const int* __restrict__ tok, const float* __restrict__ emb,
    unsigned short* __restrict__ x0)
{
  long gid = (long)blockIdx.x * 256 + threadIdx.x;
  long idx = gid * 4;                     // element index into [NS][NB][NE]
  int e = (int)(idx & 127);
  int b = (int)((idx >> 7) & 255);
  int t = (int)(idx >> 15);
  int tk = tok[b * NS + t];
  f32x4 v = *(const f32x4*)(emb + (long)tk * NE + e);
  u16x4 o;
  #pragma unroll
  for (int i = 0; i < 4; ++i) o[i] = f2bf(v[i] * 11.313708498984761f);
  *(u16x4*)(x0 + idx) = o;
}

// ---------------------------------------------------------------------------
// GEMM: C[M][N] = A[M][K] * BT[N][K]^T  (+bias, +relu, f32/bf16 out, row remap)
// m97-style: 256 thr, BK=64, global_load_lds staging, 16x16x32 bf16 MFMA
// (used for the dense head only)
// ---------------------------------------------------------------------------
template<int BM, int BN, bool BIAS, bool RELU, bool F32OUT, bool REMAP>
__global__ __launch_bounds__(256) void gemm_bt(
    const unsigned short* __restrict__ A, const unsigned short* __restrict__ BT,
    void* __restrict__ Cv, const float* __restrict__ bias,
    int M, int N, int K, int rowoff)
{
  constexpr int BK = 64;
  constexpr int WN = (BN >= 64) ? 2 : 1;
  constexpr int WM = 4 / WN;
  constexpr int WTM = BM / WM, WTN = BN / WN;
  constexpr int FM = WTM / 16, FN = WTN / 16;
  __shared__ unsigned short lds[(BM + BN) * BK];
  unsigned short* As = lds;
  unsigned short* Bs = lds + BM * BK;
  const int tid = threadIdx.x;
  const int w = tid >> 6, l = tid & 63;
  const int n0 = blockIdx.x * BN, m0 = blockIdx.y * BM;
  const int wm = (WN == 2) ? (w >> 1) : w;
  const int wn = (WN == 2) ? (w & 1) : 0;

  f32x4 acc[FM][FN];
  #pragma unroll
  for (int i = 0; i < FM; i++)
    #pragma unroll
    for (int j = 0; j < FN; j++) acc[i][j] = (f32x4)0.f;

  constexpr int CH_A = BM * 8;            // 16B chunks in A region
  constexpr int CH_T = (BM + BN) * 8;
  constexpr int PW = CH_T / 4;
  static_assert(PW % 64 == 0, "staging alignment");
  static_assert(CH_A % 64 == 0, "region boundary alignment");

  for (int kt = 0; kt < K; kt += BK) {
    #pragma unroll
    for (int i = 0; i < PW / 64; ++i) {
      int c0 = w * PW + i * 64;           // wave-uniform
      int c = c0 + l;
      const unsigned short* g;
      if (c0 < CH_A) {
        int row = c >> 3, col = c & 7;
        g = A + (long)(m0 + row) * K + kt + col * 8;
      } else {
        int cb = c - CH_A;
        int row = cb >> 3, col = cb & 7;
        g = BT + (long)(n0 + row) * K + kt + col * 8;
      }
      gload_lds16(g, lds + (size_t)c0 * 8);
    }
    __syncthreads();
    #pragma unroll
    for (int ks = 0; ks < BK / 32; ++ks) {
      short8 a[FM], b[FN];
      #pragma unroll
      for (int mt = 0; mt < FM; ++mt)
        a[mt] = *(const short8*)&As[(wm * WTM + mt * 16 + (l & 15)) * BK + ks * 32 + (l >> 4) * 8];
      #pragma unroll
      for (int nt = 0; nt < FN; ++nt)
        b[nt] = *(const short8*)&Bs[(wn * WTN + nt * 16 + (l & 15)) * BK + ks * 32 + (l >> 4) * 8];
      #pragma unroll
      for (int mt = 0; mt < FM; ++mt)
        #pragma unroll
        for (int nt = 0; nt < FN; ++nt)
          acc[mt][nt] = __builtin_amdgcn_mfma_f32_16x16x32_bf16(a[mt], b[nt], acc[mt][nt], 0, 0, 0);
    }
    __syncthreads();
  }

  const int row_l = l >> 4, col_l = l & 15;
  #pragma unroll
  for (int nt = 0; nt < FN; ++nt) {
    int col = n0 + wn * WTN + nt * 16 + col_l;
    float bv = 0.f;
    if (BIAS) bv = bias[col];
    #pragma unroll
    for (int mt = 0; mt < FM; ++mt) {
      #pragma unroll
      for (int i = 0; i < 4; ++i) {
        int m = m0 + wm * WTM + mt * 16 + row_l * 4 + i;
        float v = acc[mt][nt][i] + bv;
        if (RELU) v = v > 0.f ? v : 0.f;
        long cidx;
        if (REMAP) {
          int gr = rowoff + m;            // global time-major row = t*NB + b
          int b_ = gr & (NB - 1), t_ = gr >> 8;
          cidx = ((long)b_ * NS + t_) * N + col;
        } else {
          cidx = (long)m * N + col;
        }
        if (F32OUT) ((float*)Cv)[cidx] = v;
        else ((unsigned short*)Cv)[cidx] = f2bf(v);
      }
    }
  }
}

// ---------------------------------------------------------------------------
// Fused LSTM scan, round 7: reg-resident weights + wave specialization (kept
// from round 6) with the round-5-style parallel publish protocol restored:
//   - gates phase: EVERY thread stores its own 2 h values (sc0sc1, MALL),
//     drains, barrier, then tid0 plain-stores seq[slice] (NO atomics —
//     round 6's 32 serialized atomic_adds on one line cost ~1 us/step).
//   - zh waves poll the group's 32-word seq line with one coalesced 64-lane
//     load, __all(seq >= t); then per-lane direct dwordx4 gather of h frags
//     (h_buf layout == A-frag mapping), 64 MFMA from registers.
//   - waves 0-1: zx MFMA from persistent W regs + x[t+1] prefetch only.
// 96KB dynamic LDS pads occupancy to 1 WG/CU for uniform placement.
// seq>=t implies h[t-1] visible AND h[t-2] readers done => parity buffer safe.
// ---------------------------------------------------------------------------
#define SCAN_LDS_BYTES 98304

template<int KD>
__global__ __launch_bounds__(256, 1) void lstm_scan_fused(
    const unsigned short* __restrict__ x_in,  // [NS][NB][KD] bf16
    const unsigned short* __restrict__ WT,    // [2048][KD] bf16
    const unsigned short* __restrict__ UT,    // [2048][512] bf16
    const float* __restrict__ bias,           // [2048] f32
    unsigned short* __restrict__ x_out,       // [NS][NB][512] bf16
    unsigned short* __restrict__ h_buf,       // [2][8][16 ks][32 r][32 n] bf16
    unsigned int* __restrict__ seq)           // [8][32] (128B line per group)
{
  constexpr int KS = KD / 32;
  extern __shared__ char smem[];
  float* Zlx = (float*)smem;                  // [32][65]
  float* Zlh = (float*)(smem + 8448);         // [32][65]

  const int tid = threadIdx.x, wv = tid >> 6, l = tid & 63;
  const int group = blockIdx.x & 7;
  const int slice = blockIdx.x >> 3;
  const int u0 = slice * 16;
  const int lr = l & 15, lk = l >> 4;        // frag row / k-quad
  const int j2 = tid & 15, r0 = tid >> 4;    // gates cell mapping (r0 in 0..15)
  const int n_ = u0 + j2;
  const int wz = wv & 1;                     // gate-pair index within role

  // ---- persistent weight fragments (W for zx waves, U for zh waves)
  short8 wfrag[2][16];
  float bv0 = 0.f, bv1 = 0.f;
  if (wv < 2) {
    #pragma unroll
    for (int g = 0; g < 2; ++g)
      #pragma unroll
      for (int ks = 0; ks < KS; ++ks)
        wfrag[g][ks] = *(const short8*)(WT + (size_t)((2 * wz + g) * NH + u0 + lr) * KD + ks * 32 + lk * 8);
    bv0 = bias[(2 * wz + 0) * NH + u0 + lr];
    bv1 = bias[(2 * wz + 1) * NH + u0 + lr];
  } else {
    #pragma unroll
    for (int g = 0; g < 2; ++g)
      #pragma unroll
      for (int ks = 0; ks < 16; ++ks)
        wfrag[g][ks] = *(const short8*)(UT + (size_t)((2 * wz + g) * NH + u0 + lr) * NH + ks * 32 + lk * 8);
  }

  // ---- zx x-fragment registers, preloaded for t=0
  short8 xa[2][KS];
  const unsigned short* xp0 = x_in + (size_t)(group * 32 + lr) * KD + lk * 8;
  if (wv < 2) {
    #pragma unroll
    for (int m = 0; m < 2; ++m)
      #pragma unroll
      for (int ks = 0; ks < KS; ++ks)
        xa[m][ks] = *(const short8*)(xp0 + (size_t)m * 16 * KD + ks * 32);
  }

  // ---- pointers
  // h publish per-thread: h_buf[par][group][ks=slice>>1][r][ (slice&1)*16 + j2 ]
  const int hpub = group * 16384 + (slice >> 1) * 1024 + r0 * 32 + (slice & 1) * 16 + j2;
  const unsigned short* hb0 = h_buf + group * 16384 + lr * 32 + lk * 8;  // zh gather
  unsigned int* seqline = seq + group * 32;
  unsigned int* myseq = seqline + slice;
  const unsigned int* fp = seqline + (l & 31);

  // ---- zero Zlh (t=0 reads it)
  for (int i = tid; i < 32 * 65; i += 256) Zlh[i] = 0.f;
  __syncthreads();

  float c0 = 0.f, c1 = 0.f;

  for (int t = 0; t < NS; ++t) {
    if (wv < 2) {
      // ---- zx: MFMA from persistent regs; acc init = bias
      f32x4 a00 = {bv0, bv0, bv0, bv0}, a01 = {bv0, bv0, bv0, bv0};
      f32x4 a10 = {bv1, bv1, bv1, bv1}, a11 = {bv1, bv1, bv1, bv1};
      #pragma unroll
      for (int ks = 0; ks < KS; ++ks) {
        a00 = __builtin_amdgcn_mfma_f32_16x16x32_bf16(xa[0][ks], wfrag[0][ks], a00, 0, 0, 0);
        a01 = __builtin_amdgcn_mfma_f32_16x16x32_bf16(xa[1][ks], wfrag[0][ks], a01, 0, 0, 0);
        a10 = __builtin_amdgcn_mfma_f32_16x16x32_bf16(xa[0][ks], wfrag[1][ks], a10, 0, 0, 0);
        a11 = __builtin_amdgcn_mfma_f32_16x16x32_bf16(xa[1][ks], wfrag[1][ks], a11, 0, 0, 0);
      }
      #pragma unroll
      for (int i = 0; i < 4; ++i) {
        Zlx[(lk * 4 + i) * 65      + (2 * wz + 0) * 16 + lr] = a00[i];
        Zlx[(16 + lk * 4 + i) * 65 + (2 * wz + 0) * 16 + lr] = a01[i];
        Zlx[(lk * 4 + i) * 65      + (2 * wz + 1) * 16 + lr] = a10[i];
        Zlx[(16 + lk * 4 + i) * 65 + (2 * wz + 1) * 16 + lr] = a11[i];
      }
      // ---- prefetch x for t+1 (clamped; clamped data never consumed)
      int tn = (t + 1 < NS) ? (t + 1) : t;
      const unsigned short* xp = xp0 + (size_t)tn * NB * KD;
      #pragma unroll
      for (int m = 0; m < 2; ++m)
        #pragma unroll
        for (int ks = 0; ks < KS; ++ks)
          xa[m][ks] = *(const short8*)(xp + (size_t)m * 16 * KD + ks * 32);
    } else if (t > 0) {
      // ---- zh: poll seq line (coalesced 64-lane read), gather h, MFMA
      {
        unsigned int v; int spin = 0;
        do {
          asm volatile("global_load_dword %0, %1, off sc0 sc1\n\ts_waitcnt vmcnt(0)"
                       : "=v"(v) : "v"(fp) : "memory");
        } while (!__all(v >= (unsigned)t) && ++spin < (1 << 15));
      }
      const unsigned short* hb_ = hb0 + (size_t)((t - 1) & 1) * 131072;
      short8 ha[2][16];
      #pragma unroll
      for (int ks = 0; ks < 16; ++ks) {
        asm volatile("global_load_dwordx4 %0, %1, off sc0 sc1"
                     : "=v"(ha[0][ks]) : "v"(hb_ + ks * 1024) : "memory");
        asm volatile("global_load_dwordx4 %0, %1, off sc0 sc1"
                     : "=v"(ha[1][ks]) : "v"(hb_ + ks * 1024 + 512) : "memory");
      }
      asm volatile("s_waitcnt vmcnt(0)" ::: "memory");
      __builtin_amdgcn_sched_barrier(0);
      f32x4 a00 = (f32x4)0.f, a01 = (f32x4)0.f, a10 = (f32x4)0.f, a11 = (f32x4)0.f;
      #pragma unroll
      for (int ks = 0; ks < 16; ++ks) {
        a00 = __builtin_amdgcn_mfma_f32_16x16x32_bf16(ha[0][ks], wfrag[0][ks], a00, 0, 0, 0);
        a01 = __builtin_amdgcn_mfma_f32_16x16x32_bf16(ha[1][ks], wfrag[0][ks], a01, 0, 0, 0);
        a10 = __builtin_amdgcn_mfma_f32_16x16x32_bf16(ha[0][ks], wfrag[1][ks], a10, 0, 0, 0);
        a11 = __builtin_amdgcn_mfma_f32_16x16x32_bf16(ha[1][ks], wfrag[1][ks], a11, 0, 0, 0);
      }
      #pragma unroll
      for (int i = 0; i < 4; ++i) {
        Zlh[(lk * 4 + i) * 65      + (2 * wz + 0) * 16 + lr] = a00[i];
        Zlh[(16 + lk * 4 + i) * 65 + (2 * wz + 0) * 16 + lr] = a01[i];
        Zlh[(lk * 4 + i) * 65      + (2 * wz + 1) * 16 + lr] = a10[i];
        Zlh[(16 + lk * 4 + i) * 65 + (2 * wz + 1) * 16 + lr] = a11[i];
      }
    }
    __syncthreads();   // A: Zlx/Zlh ready

    // ---- gates (all threads; thread owns rows r0, r0+16 of col j2)
    unsigned short hsh[2];
    #pragma unroll
    for (int p = 0; p < 2; ++p) {
      int r = r0 + p * 16;
      float zi = Zlx[r * 65 +      j2] + Zlh[r * 65 +      j2];
      float zf = Zlx[r * 65 + 16 + j2] + Zlh[r * 65 + 16 + j2];
      float zg = Zlx[r * 65 + 32 + j2] + Zlh[r * 65 + 32 + j2];
      float zo = Zlx[r * 65 + 48 + j2] + Zlh[r * 65 + 48 + j2];
      float ig = 1.f / (1.f + __expf(-zi));
      float fg = 1.f / (1.f + __expf(-zf));
      float gg = 1.f - 2.f / (__expf(2.f * zg) + 1.f);   // robust tanh
      float og = 1.f / (1.f + __expf(-zo));
      float cc = fg * (p ? c1 : c0) + ig * gg;
      if (p) c1 = cc; else c0 = cc;
      float th = 1.f - 2.f / (__expf(2.f * cc) + 1.f);
      hsh[p] = f2bf(og * th);
    }
    // ---- publish h[t] (sc0sc1, parity t&1) + x_out (cached path)
    {
      unsigned short* hp = h_buf + (size_t)(t & 1) * 131072 + hpub;
      unsigned int s0 = hsh[0], s1 = hsh[1];
      asm volatile("global_store_short %0, %1, off sc0 sc1"
                   :: "v"(hp), "v"(s0) : "memory");
      asm volatile("global_store_short %0, %1, off sc0 sc1"
                   :: "v"(hp + 512), "v"(s1) : "memory");
      x_out[((size_t)t * NB + group * 32 + r0) * NH + n_] = hsh[0];
      x_out[((size_t)t * NB + group * 32 + r0 + 16) * NH + n_] = hsh[1];
      asm volatile("s_waitcnt vmcnt(0)" ::: "memory");
    }
    __syncthreads();   // B: all h[t] stores drained (and Zl reads done)
    if (tid == 0) {
      unsigned int nv = (unsigned int)(t + 1);
      asm volatile("global_store_dword %0, %1, off sc0 sc1"
                   :: "v"(myseq), "v"(nv) : "memory");
    }
  }
}

// ---------------------------------------------------------------------------
extern "C" void kernel_launch(void* const* d_in, const int* in_sizes, int n_in,
                              void* d_out, int out_size, void* d_ws, size_t ws_size,
                              hipStream_t stream) {
  const int*   tokens = (const int*)  d_in[0];
  const float* emb    = (const float*)d_in[1];
  const float* w0     = (const float*)d_in[2];
  const float* u0     = (const float*)d_in[3];
  const float* b0     = (const float*)d_in[4];
  const float* w_rest = (const float*)d_in[5];
  const float* u_rest = (const float*)d_in[6];
  const float* b_rest = (const float*)d_in[7];
  const float* dw1    = (const float*)d_in[8];
  const float* db1    = (const float*)d_in[9];
  const float* dw2    = (const float*)d_in[10];
  const float* db2    = (const float*)d_in[11];
  float* out = (float*)d_out;

  char* ws = (char*)d_ws;
  size_t off = 0;
  auto alloc = [&](size_t bytes) -> char* {
    char* p = ws + off;
    off += (bytes + 255) & ~(size_t)255;
    return p;
  };
  unsigned short* ut[4];
  for (int i = 0; i < 4; ++i) ut[i] = (unsigned short*)alloc((size_t)N4H * NH * 2);
  unsigned short* w0t = (unsigned short*)alloc((size_t)N4H * NE * 2);
  unsigned short* wt[3];
  for (int i = 0; i < 3; ++i) wt[i] = (unsigned short*)alloc((size_t)N4H * NH * 2);
  unsigned short* dw1t = (unsigned short*)alloc((size_t)1024 * 512 * 2);
  unsigned short* dw2t = (unsigned short*)alloc((size_t)32 * 1024 * 2);
  unsigned short* x0  = (unsigned short*)alloc((size_t)NB * NS * NE * 2);
  unsigned short* xA  = (unsigned short*)alloc((size_t)NB * NS * NH * 2);
  unsigned short* hb  = (unsigned short*)alloc((size_t)2 * 8 * 16384 * 2);
  unsigned int*  seq  = (unsigned int*)alloc((size_t)4 * 8 * 32 * 4);

  // head intermediate chunk buffer from remaining workspace
  size_t avail = (ws_size > off) ? (ws_size - off) : 0;
  long RC = (long)(avail / ((size_t)1024 * 2));
  if (RC > (long)NB * NS) RC = (long)NB * NS;
  RC &= ~(long)127;
  if (RC < 128) RC = 128;
  unsigned short* h1buf = (unsigned short*)alloc((size_t)RC * 1024 * 2);

  (void)hipMemsetAsync(seq, 0, (size_t)4 * 8 * 32 * 4, stream);

  // Weight transposes (f32 [K][N] -> bf16 [N][K])
  transpose_cast<<<dim3(1, N4H), 256, 0, stream>>>(w0, w0t, NE, N4H);
  transpose_cast<<<dim3(2, N4H), 256, 0, stream>>>(u0, ut[0], NH, N4H);
  for (int i = 0; i < 3; ++i) {
    transpose_cast<<<dim3(2, N4H), 256, 0, stream>>>(w_rest + (size_t)i * NH * N4H, wt[i], NH, N4H);
    transpose_cast<<<dim3(2, N4H), 256, 0, stream>>>(u_rest + (size_t)i * NH * N4H, ut[i + 1], NH, N4H);
  }
  transpose_cast<<<dim3(2, 1024), 256, 0, stream>>>(dw1, dw1t, 512, 1024);
  transpose_cast<<<dim3(4, 32), 256, 0, stream>>>(dw2, dw2t, 1024, 32);

  embed_kernel<<<16384, 256, 0, stream>>>(tokens, emb, x0);

  (void)hipFuncSetAttribute((const void*)lstm_scan_fused<NE>,
                            hipFuncAttributeMaxDynamicSharedMemorySize, SCAN_LDS_BYTES);
  (void)hipFuncSetAttribute((const void*)lstm_scan_fused<NH>,
                            hipFuncAttributeMaxDynamicSharedMemorySize, SCAN_LDS_BYTES);

  // Layer 0: x0 -> xA ; layers 1-3: xA -> xA in place (protocol-ordered)
  lstm_scan_fused<NE><<<256, 256, SCAN_LDS_BYTES, stream>>>(
      x0, w0t, ut[0], b0, xA, hb, seq);
  for (int lyr = 1; lyr < 4; ++lyr) {
    lstm_scan_fused<NH><<<256, 256, SCAN_LDS_BYTES, stream>>>(
        xA, wt[lyr - 1], ut[lyr], b_rest + (size_t)(lyr - 1) * N4H, xA, hb,
        seq + (size_t)lyr * 8 * 32);
  }

  // Dense head, row-chunked through h1buf: h1 = relu(x@dw1+db1); out = h1@dw2+db2
  for (long r0 = 0; r0 < (long)NB * NS; r0 += RC) {
    long rows = ((long)NB * NS - r0 < RC) ? ((long)NB * NS - r0) : RC;
    gemm_bt<128, 128, true, true, false, false>
        <<<dim3(1024 / 128, rows / 128), 256, 0, stream>>>(
            xA + (size_t)r0 * NH, dw1t, h1buf, db1, (int)rows, 1024, NH, 0);
    gemm_bt<128, 32, true, false, true, true>
        <<<dim3(1, rows / 128), 256, 0, stream>>>(
            h1buf, dw2t, out, db2, (int)rows, 32, 1024, (int)r0);
  }
}